// Round 6
// baseline (325.982 us; speedup 1.0000x reference)
//
#include <hip/hip_runtime.h>

// B=8, T=S=512, M=N=512, H=128
// score = (Sv - 2*sum_h v_h * sigma_h)/SCALE, sigma = 1/(1+2^z), z = 2log2e*(x1+x2)
// proj stores q = 2^(z_i/4) (fp32, clamped exponent +-126 -> never 0/inf/NaN).
// Hot loop (all scalar fp32, NO inline asm):
//   p = q_t*q_s            (= 2^(z/4), may overflow to +inf -- handled)
//   pp = p*p               (= 2^(z/2))
//   c = fmed3(pp,0,2^7.5)  (= min(2^(z/2), 2^7.5); med3 kills inf deterministically)
//   A = fma(c,c,1)         (= 1 + min(2^z, 2^15); sigma err < 2^-15 when clamped)
// 8-way-over-h rcp merge: sum v_i/A_i = num/prod(A), one rcp per 8 evals.

typedef float vf2 __attribute__((ext_vector_type(2)));

constexpr float SCALE_IN  = 2.8853900817779268f;   // 2*log2(e)
constexpr float INV_SCALE = 0.04419417382415922f;  // 1/sqrt(512)
constexpr float CLAMP_HI  = 181.01933598375617f;   // 2^7.5

// ---------------- Projection GEMM -> q-representation ------------------------
// Grid 512 (256/matrix), 256 threads, 16 rows x 128 h per block.
// Register-prefetched staging. Tile 2r x 4h.
__global__ __launch_bounds__(256, 2) void proj_kernel(
    const float* __restrict__ q,  const float* __restrict__ w2,
    const float* __restrict__ ky, const float* __restrict__ w1,
    float* __restrict__ x1q, float* __restrict__ x2q) {
  __shared__ float As[16 * 68];     // +4 pad
  __shared__ float Ws[64 * 128];

  int blk = blockIdx.x;
  const float* A; const float* W; float* O;
  if (blk < 256) { A = q;  W = w2; O = x1q; }
  else { blk -= 256; A = ky; W = w1; O = x2q; }
  const int rbase = blk * 16;
  const int tid = threadIdx.x;

  const int arow = tid >> 4, ak = (tid & 15) * 4;
  const int wrow = tid >> 5, wh = (tid & 31) * 4;
  const int rg = tid >> 5;
  const int hq = (tid & 31) * 4;

  const float* Ab = A + (size_t)(rbase + arow) * 512 + ak;
  const float* Wb = W + (size_t)wrow * 128 + wh;

  float4 pa, pw[8];
  pa = *(const float4*)Ab;
#pragma unroll
  for (int p = 0; p < 8; ++p) pw[p] = *(const float4*)(Wb + (size_t)(8 * p) * 128);

  float acc[2][4];
#pragma unroll
  for (int r = 0; r < 2; ++r)
#pragma unroll
    for (int c = 0; c < 4; ++c) acc[r][c] = 0.0f;

  for (int c = 0; c < 8; ++c) {
    __syncthreads();
    *(float4*)(As + arow * 68 + ak) = pa;
#pragma unroll
    for (int p = 0; p < 8; ++p)
      *(float4*)(Ws + (wrow + 8 * p) * 128 + wh) = pw[p];
    __syncthreads();
    if (c < 7) {
      const int kb = 64 * (c + 1);
      pa = *(const float4*)(Ab + kb);
#pragma unroll
      for (int p = 0; p < 8; ++p)
        pw[p] = *(const float4*)(Wb + (size_t)(kb + 8 * p) * 128);
    }
#pragma unroll 4
    for (int k4 = 0; k4 < 64; k4 += 4) {
      float a0[4], a1[4], w[4][4];
      *(float4*)a0 = *(const float4*)(As + (2 * rg + 0) * 68 + k4);
      *(float4*)a1 = *(const float4*)(As + (2 * rg + 1) * 68 + k4);
#pragma unroll
      for (int kk = 0; kk < 4; ++kk)
        *(float4*)w[kk] = *(const float4*)(Ws + (k4 + kk) * 128 + hq);
#pragma unroll
      for (int kk = 0; kk < 4; ++kk)
#pragma unroll
        for (int cc = 0; cc < 4; ++cc) {
          acc[0][cc] = fmaf(a0[kk], w[kk][cc], acc[0][cc]);
          acc[1][cc] = fmaf(a1[kk], w[kk][cc], acc[1][cc]);
        }
    }
  }

  // q = exp2(clamp(z/4, +-126)) in [2^-126, 2^126] -- never 0/inf/NaN
#pragma unroll
  for (int r = 0; r < 2; ++r) {
    float4 o;
    float* op = (float*)&o;
#pragma unroll
    for (int cc = 0; cc < 4; ++cc) {
      float zq = acc[r][cc] * (SCALE_IN * 0.25f);
      zq = __builtin_amdgcn_fmed3f(zq, -126.0f, 126.0f);
      op[cc] = __builtin_amdgcn_exp2f(zq);
    }
    *(float4*)(O + (size_t)(rbase + 2 * rg + r) * 128 + hq) = o;
  }
}

// ---------------- Main score kernel -----------------------------------------
// Grid 1024, 256 threads, launch_bounds(256,4) -> <=128 VGPR, 4 blocks/CU.
// Tile 64t x 32s, thread 4t x 2s. LDS 13KB per 32-h chunk:
//   x1l [h][t] stride 68 (rows 16B-aligned; staged writes 2-way max = free;
//   b128 reads broadcast), x2l [h][s] stride 34 (b64 reads broadcast).
__global__ __launch_bounds__(256, 4) void score_kernel(
    const float* __restrict__ x1q, const float* __restrict__ x2q,
    const float* __restrict__ v, float* __restrict__ out) {
  __shared__ float x1l[32 * 68];
  __shared__ float x2l[32 * 34];

  const int tid   = threadIdx.x;
  const int b     = blockIdx.x >> 7;
  const int tile  = blockIdx.x & 127;
  const int tbase = (tile >> 4) * 64;
  const int sbase = (tile & 15) * 32;

  const int sg = tid & 15;          // s = 2sg+{0,1}
  const int tg = tid >> 4;          // t = 4tg+{0..3}

  const int t1 = tid >> 2, f1 = tid & 3;   // x1 staging
  const int s2 = tid >> 3, f2 = tid & 7;   // x2 staging

  const float* x1g = x1q + (size_t)(b * 512 + tbase + t1) * 128;
  const float* x2g = x2q + (size_t)(b * 512 + sbase + s2) * 128;

  float sv = 0.0f;                           // uniform: s_loads + few VALU adds
  for (int i = 0; i < 128; i += 4) {
    const float4 vx = *(const float4*)(v + i);
    sv += (vx.x + vx.y) + (vx.z + vx.w);
  }

  float racc[4][2];
#pragma unroll
  for (int i = 0; i < 4; ++i) { racc[i][0] = 0.0f; racc[i][1] = 0.0f; }

  float4 pa0, pa1, pb;
  pa0 = *(const float4*)(x1g + 4 * f1);
  pa1 = *(const float4*)(x1g + 16 + 4 * f1);
  pb  = *(const float4*)(x2g + 4 * f2);

  for (int c = 0; c < 4; ++c) {
    __syncthreads();
    {
      const float* s4 = (const float*)&pa0;
      const float* s5 = (const float*)&pa1;
#pragma unroll
      for (int j = 0; j < 4; ++j) {
        x1l[(4 * f1 + j) * 68 + t1]        = s4[j];
        x1l[(16 + 4 * f1 + j) * 68 + t1]   = s5[j];
      }
      const float* s6 = (const float*)&pb;
#pragma unroll
      for (int j = 0; j < 4; ++j)
        x2l[(4 * f2 + j) * 34 + s2] = s6[j];
    }
    __syncthreads();
    if (c < 3) {
      const int hb = 32 * (c + 1);
      pa0 = *(const float4*)(x1g + hb + 4 * f1);
      pa1 = *(const float4*)(x1g + hb + 16 + 4 * f1);
      pb  = *(const float4*)(x2g + hb + 4 * f2);
    }

#pragma unroll
    for (int hg = 0; hg < 4; ++hg) {
      const int h0 = 8 * hg;
      float qt[8][4]; float qs[8][2]; float vh[8];
#pragma unroll
      for (int qq = 0; qq < 8; ++qq) {
        *(float4*)qt[qq] = *(const float4*)(x1l + (h0 + qq) * 68 + 4 * tg);
        *(vf2*)qs[qq]    = *(const vf2*)(x2l + (h0 + qq) * 34 + 2 * sg);
        vh[qq] = v[32 * c + h0 + qq];            // uniform -> s_load
      }

#pragma unroll
      for (int i = 0; i < 4; ++i) {
#pragma unroll
        for (int j = 0; j < 2; ++j) {
          float A[8];
#pragma unroll
          for (int qq = 0; qq < 8; ++qq) {
            const float p  = qt[qq][i] * qs[qq][j];
            const float pp = p * p;
            const float cc = __builtin_amdgcn_fmed3f(pp, 0.0f, CLAMP_HI);
            A[qq] = fmaf(cc, cc, 1.0f);          // in [1, 32769]
          }
          const float n01 = fmaf(vh[1], A[0], vh[0] * A[1]);
          const float d01 = A[0] * A[1];
          const float n23 = fmaf(vh[3], A[2], vh[2] * A[3]);
          const float d23 = A[2] * A[3];
          const float n45 = fmaf(vh[5], A[4], vh[4] * A[5]);
          const float d45 = A[4] * A[5];
          const float n67 = fmaf(vh[7], A[6], vh[6] * A[7]);
          const float d67 = A[6] * A[7];
          const float n03 = fmaf(n23, d01, n01 * d23);
          const float d03 = d01 * d23;
          const float n47 = fmaf(n67, d45, n45 * d67);
          const float d47 = d45 * d67;
          const float num = fmaf(n47, d03, n03 * d47);
          const float den = d03 * d47;           // in [1, 2^120.01]
          racc[i][j] = fmaf(num, __builtin_amdgcn_rcpf(den), racc[i][j]);
        }
      }
    }
  }

  const float c1 = sv * INV_SCALE;
  const float c2 = -2.0f * INV_SCALE;
#pragma unroll
  for (int i = 0; i < 4; ++i) {
    vf2 o;
    o.x = fmaf(racc[i][0], c2, c1);
    o.y = fmaf(racc[i][1], c2, c1);
    *(vf2*)(out + (size_t)(b * 512 + tbase + 4 * tg + i) * 512 + sbase + 2 * sg) = o;
  }
}

extern "C" void kernel_launch(void* const* d_in, const int* in_sizes, int n_in,
                              void* d_out, int out_size, void* d_ws, size_t ws_size,
                              hipStream_t stream) {
  const float* query = (const float*)d_in[0];  // (8,512,512)
  const float* keys  = (const float*)d_in[1];  // (8,512,512)
  const float* W1    = (const float*)d_in[2];  // (512,128) pairs with keys
  const float* W2    = (const float*)d_in[3];  // (512,128) pairs with query
  const float* v     = (const float*)d_in[4];  // (128,)
  float* out = (float*)d_out;                  // (8,512,512) fp32

  float* x1q = (float*)d_ws;                   // 2 MB
  float* x2q = x1q + 8 * 512 * 128;            // 2 MB

  hipLaunchKernelGGL(proj_kernel, dim3(512), dim3(256), 0, stream,
                     query, W2, keys, W1, x1q, x2q);
  hipLaunchKernelGGL(score_kernel, dim3(1024), dim3(256), 0, stream,
                     x1q, x2q, v, out);
}

// Round 7
// 299.622 us; speedup vs baseline: 1.0880x; 1.0880x over previous
//
#include <hip/hip_runtime.h>

// B=8, T=S=512, M=N=512, H=128
// score = (Sv - 2*sum_h v_h * sigma_h)/SCALE, sigma = 1/(1+2^z), z = 2log2e*(x1+x2)
// proj stores q = 2^(z_i/4) (fp32, clamped exponent +-126 -> never 0/inf/NaN).
// Hot loop (scalar fp32):
//   p = q_t*q_s; pp = p*p; c = fmed3(pp,0,2^7.5); A = fma(c,c,1)
//   == 1 + min(2^z, 2^15), sigma err < 2^-15 when clamped. med3 kills inf.
// 8-way-over-h rcp merge: sum v_i/A_i = num/prod(A), one rcp per 8 evals.
// ALL local arrays are ext_vector types (vf4/vf2) -- no address-taken locals,
// no scratch spill (round 6: float[][] + *(float4*)cast put 1 GB on scratch).

typedef float vf2 __attribute__((ext_vector_type(2)));
typedef float vf4 __attribute__((ext_vector_type(4)));

constexpr float SCALE_IN  = 2.8853900817779268f;   // 2*log2(e)
constexpr float INV_SCALE = 0.04419417382415922f;  // 1/sqrt(512)
constexpr float CLAMP_HI  = 181.01933598375617f;   // 2^7.5

// ---------------- Projection GEMM -> q-representation ------------------------
// Grid 512 (256/matrix), 256 threads, 16 rows x 128 h per block.
// Register-prefetched staging. Tile 2r x 4h.
__global__ __launch_bounds__(256, 2) void proj_kernel(
    const float* __restrict__ q,  const float* __restrict__ w2,
    const float* __restrict__ ky, const float* __restrict__ w1,
    float* __restrict__ x1q, float* __restrict__ x2q) {
  __shared__ float As[16 * 68];     // +4 pad
  __shared__ float Ws[64 * 128];

  int blk = blockIdx.x;
  const float* A; const float* W; float* O;
  if (blk < 256) { A = q;  W = w2; O = x1q; }
  else { blk -= 256; A = ky; W = w1; O = x2q; }
  const int rbase = blk * 16;
  const int tid = threadIdx.x;

  const int arow = tid >> 4, ak = (tid & 15) * 4;
  const int wrow = tid >> 5, wh = (tid & 31) * 4;
  const int rg = tid >> 5;
  const int hq = (tid & 31) * 4;

  const float* Ab = A + (size_t)(rbase + arow) * 512 + ak;
  const float* Wb = W + (size_t)wrow * 128 + wh;

  vf4 pa, pw[8];
  pa = *(const vf4*)Ab;
#pragma unroll
  for (int p = 0; p < 8; ++p) pw[p] = *(const vf4*)(Wb + (size_t)(8 * p) * 128);

  float acc[2][4];
#pragma unroll
  for (int r = 0; r < 2; ++r)
#pragma unroll
    for (int c = 0; c < 4; ++c) acc[r][c] = 0.0f;

  for (int c = 0; c < 8; ++c) {
    __syncthreads();
    *(vf4*)(As + arow * 68 + ak) = pa;
#pragma unroll
    for (int p = 0; p < 8; ++p)
      *(vf4*)(Ws + (wrow + 8 * p) * 128 + wh) = pw[p];
    __syncthreads();
    if (c < 7) {
      const int kb = 64 * (c + 1);
      pa = *(const vf4*)(Ab + kb);
#pragma unroll
      for (int p = 0; p < 8; ++p)
        pw[p] = *(const vf4*)(Wb + (size_t)(kb + 8 * p) * 128);
    }
#pragma unroll 4
    for (int k4 = 0; k4 < 64; k4 += 4) {
      vf4 a0, a1, w[4];
      a0 = *(const vf4*)(As + (2 * rg + 0) * 68 + k4);
      a1 = *(const vf4*)(As + (2 * rg + 1) * 68 + k4);
#pragma unroll
      for (int kk = 0; kk < 4; ++kk)
        w[kk] = *(const vf4*)(Ws + (k4 + kk) * 128 + hq);
#pragma unroll
      for (int kk = 0; kk < 4; ++kk)
#pragma unroll
        for (int cc = 0; cc < 4; ++cc) {
          acc[0][cc] = fmaf(a0[kk], w[kk][cc], acc[0][cc]);
          acc[1][cc] = fmaf(a1[kk], w[kk][cc], acc[1][cc]);
        }
    }
  }

  // q = exp2(clamp(z/4, +-126)) in [2^-126, 2^126] -- never 0/inf/NaN
#pragma unroll
  for (int r = 0; r < 2; ++r) {
    vf4 o;
#pragma unroll
    for (int cc = 0; cc < 4; ++cc) {
      float zq = acc[r][cc] * (SCALE_IN * 0.25f);
      zq = __builtin_amdgcn_fmed3f(zq, -126.0f, 126.0f);
      o[cc] = __builtin_amdgcn_exp2f(zq);
    }
    *(vf4*)(O + (size_t)(rbase + 2 * rg + r) * 128 + hq) = o;
  }
}

// ---------------- Main score kernel -----------------------------------------
// Grid 1024, 256 threads. Tile 64t x 32s, thread 4t x 2s. LDS 13KB per
// 32-h chunk: x1l [h][t] stride 68, x2l [h][s] stride 34.
__global__ __launch_bounds__(256, 4) void score_kernel(
    const float* __restrict__ x1q, const float* __restrict__ x2q,
    const float* __restrict__ v, float* __restrict__ out) {
  __shared__ float x1l[32 * 68];
  __shared__ float x2l[32 * 34];

  const int tid   = threadIdx.x;
  const int b     = blockIdx.x >> 7;
  const int tile  = blockIdx.x & 127;
  const int tbase = (tile >> 4) * 64;
  const int sbase = (tile & 15) * 32;

  const int sg = tid & 15;          // s = 2sg+{0,1}
  const int tg = tid >> 4;          // t = 4tg+{0..3}

  const int t1 = tid >> 2, f1 = tid & 3;   // x1 staging
  const int s2 = tid >> 3, f2 = tid & 7;   // x2 staging

  const float* x1g = x1q + (size_t)(b * 512 + tbase + t1) * 128;
  const float* x2g = x2q + (size_t)(b * 512 + sbase + s2) * 128;

  float sv = 0.0f;                           // uniform: s_loads
  for (int i = 0; i < 128; i += 4) {
    const vf4 vx = *(const vf4*)(v + i);
    sv += (vx[0] + vx[1]) + (vx[2] + vx[3]);
  }

  float racc[4][2];
#pragma unroll
  for (int i = 0; i < 4; ++i) { racc[i][0] = 0.0f; racc[i][1] = 0.0f; }

  vf4 pa0, pa1, pb;
  pa0 = *(const vf4*)(x1g + 4 * f1);
  pa1 = *(const vf4*)(x1g + 16 + 4 * f1);
  pb  = *(const vf4*)(x2g + 4 * f2);

  for (int c = 0; c < 4; ++c) {
    __syncthreads();
#pragma unroll
    for (int j = 0; j < 4; ++j) {
      x1l[(4 * f1 + j) * 68 + t1]      = pa0[j];
      x1l[(16 + 4 * f1 + j) * 68 + t1] = pa1[j];
    }
#pragma unroll
    for (int j = 0; j < 4; ++j)
      x2l[(4 * f2 + j) * 34 + s2] = pb[j];
    __syncthreads();
    if (c < 3) {
      const int hb = 32 * (c + 1);
      pa0 = *(const vf4*)(x1g + hb + 4 * f1);
      pa1 = *(const vf4*)(x1g + hb + 16 + 4 * f1);
      pb  = *(const vf4*)(x2g + hb + 4 * f2);
    }

#pragma unroll
    for (int hg = 0; hg < 4; ++hg) {
      const int h0 = 8 * hg;
      vf4 qt[8]; vf2 qs[8]; float vh[8];
#pragma unroll
      for (int qq = 0; qq < 8; ++qq) {
        qt[qq] = *(const vf4*)(x1l + (h0 + qq) * 68 + 4 * tg);
        qs[qq] = *(const vf2*)(x2l + (h0 + qq) * 34 + 2 * sg);
        vh[qq] = v[32 * c + h0 + qq];            // uniform -> s_load
      }

#pragma unroll
      for (int i = 0; i < 4; ++i) {
#pragma unroll
        for (int j = 0; j < 2; ++j) {
          float A[8];
#pragma unroll
          for (int qq = 0; qq < 8; ++qq) {
            const float p  = qt[qq][i] * qs[qq][j];
            const float pp = p * p;
            const float cc = __builtin_amdgcn_fmed3f(pp, 0.0f, CLAMP_HI);
            A[qq] = fmaf(cc, cc, 1.0f);          // in [1, 32769]
          }
          const float n01 = fmaf(vh[1], A[0], vh[0] * A[1]);
          const float d01 = A[0] * A[1];
          const float n23 = fmaf(vh[3], A[2], vh[2] * A[3]);
          const float d23 = A[2] * A[3];
          const float n45 = fmaf(vh[5], A[4], vh[4] * A[5]);
          const float d45 = A[4] * A[5];
          const float n67 = fmaf(vh[7], A[6], vh[6] * A[7]);
          const float d67 = A[6] * A[7];
          const float n03 = fmaf(n23, d01, n01 * d23);
          const float d03 = d01 * d23;
          const float n47 = fmaf(n67, d45, n45 * d67);
          const float d47 = d45 * d67;
          const float num = fmaf(n47, d03, n03 * d47);
          const float den = d03 * d47;           // in [1, 2^120.01]
          racc[i][j] = fmaf(num, __builtin_amdgcn_rcpf(den), racc[i][j]);
        }
      }
    }
  }

  const float c1 = sv * INV_SCALE;
  const float c2 = -2.0f * INV_SCALE;
#pragma unroll
  for (int i = 0; i < 4; ++i) {
    vf2 o;
    o.x = fmaf(racc[i][0], c2, c1);
    o.y = fmaf(racc[i][1], c2, c1);
    *(vf2*)(out + (size_t)(b * 512 + tbase + 4 * tg + i) * 512 + sbase + 2 * sg) = o;
  }
}

extern "C" void kernel_launch(void* const* d_in, const int* in_sizes, int n_in,
                              void* d_out, int out_size, void* d_ws, size_t ws_size,
                              hipStream_t stream) {
  const float* query = (const float*)d_in[0];  // (8,512,512)
  const float* keys  = (const float*)d_in[1];  // (8,512,512)
  const float* W1    = (const float*)d_in[2];  // (512,128) pairs with keys
  const float* W2    = (const float*)d_in[3];  // (512,128) pairs with query
  const float* v     = (const float*)d_in[4];  // (128,)
  float* out = (float*)d_out;                  // (8,512,512) fp32

  float* x1q = (float*)d_ws;                   // 2 MB
  float* x2q = x1q + 8 * 512 * 128;            // 2 MB

  hipLaunchKernelGGL(proj_kernel, dim3(512), dim3(256), 0, stream,
                     query, W2, keys, W1, x1q, x2q);
  hipLaunchKernelGGL(score_kernel, dim3(1024), dim3(256), 0, stream,
                     x1q, x2q, v, out);
}